// Round 1
// baseline (65.752 us; speedup 1.0000x reference)
//
#include <hip/hip_runtime.h>

typedef __attribute__((ext_vector_type(4))) float f32x4;
typedef __attribute__((ext_vector_type(8))) short short8;
typedef __attribute__((ext_vector_type(4))) unsigned short ushort4v;

#define M_ROWS 16384
#define KDIM 512
#define UDIM 512
#define IN_STRIDE 1024   // inputs is (B, 2*D)
#define BM 128
#define BK 32
#define NJ 128           // jj (combined-col) width per block = 64 u-cols * 2 mats
#define LDSS 40          // LDS row stride in bf16 elements (80 B, multiple of 16 B)
#define NSTEP (KDIM / BK)

__device__ __forceinline__ unsigned short f2bf(float f) {
    union { float f; unsigned u; } v; v.f = f;
    unsigned r = v.u + 0x7FFFu + ((v.u >> 16) & 1u);  // round-to-nearest-even
    return (unsigned short)(r >> 16);
}

__global__ __launch_bounds__(256) void gru_fused(
    const float* __restrict__ inp,   // (16384, 1024)
    const float* __restrict__ w_z,   // (512, 512)
    const float* __restrict__ b_z,   // (512)
    const float* __restrict__ w_h,   // (512, 512)
    const float* __restrict__ b_h,   // (512)
    float* __restrict__ out)         // fwd (16384*1024) then seq (16384*512)
{
    __shared__ __align__(16) unsigned short Asl[2][BM][LDSS];
    __shared__ __align__(16) unsigned short Bsl[2][NJ][LDSS];

    const int tid  = threadIdx.x;
    const int lane = tid & 63;
    const int wid  = tid >> 6;
    const int wm   = wid >> 1;   // 0..1 : row half
    const int wn   = wid & 1;    // 0..1 : jj half

    const int u0   = blockIdx.x * 64;   // 8 u-blocks
    const int brow = blockIdx.y * BM;   // 128 row-blocks

    f32x4 acc[4][4];
#pragma unroll
    for (int m = 0; m < 4; ++m)
#pragma unroll
        for (int n = 0; n < 4; ++n)
            acc[m][n] = (f32x4){0.f, 0.f, 0.f, 0.f};

    f32x4 rA[4];
    f32x4 rB[4];

    // A: 128 rows x 32 k, fp32 float4 along k (coalesced, rows of inputs)
    // B: 32 k x 128 jj; jj group g=jj>>5: g&1 -> w_h else w_z, u = u0+((jj>>6)<<5)+(jj&31)
    //    each thread gathers a k-quad for one jj (lanes consecutive jj -> coalesced along u)
#define STAGE_LOAD(kt)                                                          \
    {                                                                           \
        const int k0_ = (kt) * BK;                                              \
        _Pragma("unroll")                                                       \
        for (int it = 0; it < 4; ++it) {                                        \
            int idx = tid + 256 * it;                                           \
            int r = idx >> 3, c = (idx & 7) << 2;                               \
            rA[it] = *reinterpret_cast<const f32x4*>(                           \
                inp + (size_t)(brow + r) * IN_STRIDE + k0_ + c);                \
        }                                                                       \
        _Pragma("unroll")                                                       \
        for (int it = 0; it < 4; ++it) {                                        \
            int idx = tid + 256 * it;                                           \
            int jj = idx & 127;                                                 \
            int k4 = (idx >> 7) << 2;                                           \
            const float* w_ = ((jj >> 5) & 1) ? w_h : w_z;                      \
            int u_ = u0 + ((jj >> 6) << 5) + (jj & 31);                         \
            const float* p_ = w_ + (size_t)(k0_ + k4) * UDIM + u_;              \
            rB[it][0] = p_[0];                                                  \
            rB[it][1] = p_[UDIM];                                               \
            rB[it][2] = p_[2 * UDIM];                                           \
            rB[it][3] = p_[3 * UDIM];                                           \
        }                                                                       \
    }

#define STAGE_WRITE(bufi)                                                       \
    {                                                                           \
        _Pragma("unroll")                                                       \
        for (int it = 0; it < 4; ++it) {                                        \
            int idx = tid + 256 * it;                                           \
            int r = idx >> 3, c = (idx & 7) << 2;                               \
            ushort4v v;                                                         \
            v[0] = f2bf(rA[it][0]); v[1] = f2bf(rA[it][1]);                     \
            v[2] = f2bf(rA[it][2]); v[3] = f2bf(rA[it][3]);                     \
            *reinterpret_cast<ushort4v*>(&Asl[bufi][r][c]) = v;                 \
        }                                                                       \
        _Pragma("unroll")                                                       \
        for (int it = 0; it < 4; ++it) {                                        \
            int idx = tid + 256 * it;                                           \
            int jj = idx & 127;                                                 \
            int k4 = (idx >> 7) << 2;                                           \
            ushort4v v;                                                         \
            v[0] = f2bf(rB[it][0]); v[1] = f2bf(rB[it][1]);                     \
            v[2] = f2bf(rB[it][2]); v[3] = f2bf(rB[it][3]);                     \
            *reinterpret_cast<ushort4v*>(&Bsl[bufi][jj][k4]) = v;               \
        }                                                                       \
    }

    STAGE_LOAD(0);
    STAGE_WRITE(0);

    const int fr   = lane & 15;
    const int koff = (lane >> 4) << 3;

    for (int kt = 0; kt < NSTEP; ++kt) {
        if (kt + 1 < NSTEP) STAGE_LOAD(kt + 1);   // loads in flight across compute
        __syncthreads();                           // lds[kt&1] writes visible
        const int buf = kt & 1;
        short8 af[4], bfr[4];
#pragma unroll
        for (int m = 0; m < 4; ++m)
            af[m] = *reinterpret_cast<const short8*>(&Asl[buf][wm * 64 + m * 16 + fr][koff]);
#pragma unroll
        for (int n = 0; n < 4; ++n)
            bfr[n] = *reinterpret_cast<const short8*>(&Bsl[buf][wn * 64 + n * 16 + fr][koff]);
#pragma unroll
        for (int m = 0; m < 4; ++m)
#pragma unroll
            for (int n = 0; n < 4; ++n)
                acc[m][n] = __builtin_amdgcn_mfma_f32_16x16x32_bf16(af[m], bfr[n], acc[m][n], 0, 0, 0);
        if (kt + 1 < NSTEP) STAGE_WRITE((kt + 1) & 1);  // other buffer: no read hazard
    }

    // ---- epilogue: seq = sigmoid(accz + bz) * tanh(acch + bh) ----
    float* fwd = out;
    float* seq = out + (size_t)M_ROWS * 1024;
    const int fq = lane >> 4;
#pragma unroll
    for (int p = 0; p < 2; ++p) {
        int u = u0 + wn * 32 + p * 16 + fr;
        float bz = b_z[u];
        float bh = b_h[u];
#pragma unroll
        for (int m = 0; m < 4; ++m) {
            int row0 = brow + wm * 64 + m * 16 + fq * 4;
            f32x4 az = acc[m][p];       // z-gate pre-activation
            f32x4 ah = acc[m][p + 2];   // h-candidate pre-activation
#pragma unroll
            for (int j = 0; j < 4; ++j) {
                float zt = 1.f / (1.f + __expf(-(az[j] + bz)));
                float e  = __expf(2.f * (ah[j] + bh));
                float ht = 1.f - 2.f / (e + 1.f);   // tanh
                float s  = zt * ht;
                size_t rr = (size_t)(row0 + j);
                fwd[rr * 1024 + u]       = s;    // h_t_forward[:, :512]
                fwd[rr * 1024 + 512 + u] = 0.f;  // h_t_forward[:, 512:] = out_mask = 0
                seq[rr * 512 + u]        = s;    // h_t_seq
            }
        }
    }
}

extern "C" void kernel_launch(void* const* d_in, const int* in_sizes, int n_in,
                              void* d_out, int out_size, void* d_ws, size_t ws_size,
                              hipStream_t stream) {
    const float* inp = (const float*)d_in[0];
    // d_in[1] = h (unused: h_masked == 0)
    const float* w_z = (const float*)d_in[2];
    // d_in[3] = u_z (unused)
    const float* b_z = (const float*)d_in[4];
    // d_in[5..7] = w_r, u_r, b_r (unused: r_t * h_masked == 0)
    const float* w_h = (const float*)d_in[8];
    // d_in[9] = u_h (unused)
    const float* b_h = (const float*)d_in[10];
    float* out = (float*)d_out;

    dim3 grid(UDIM / 64, M_ROWS / BM);   // (8, 128)
    dim3 block(256);
    hipLaunchKernelGGL(gru_fused, grid, block, 0, stream,
                       inp, w_z, b_z, w_h, b_h, out);
}

// Round 2
// 54.037 us; speedup vs baseline: 1.2168x; 1.2168x over previous
//
#include <hip/hip_runtime.h>

typedef __attribute__((ext_vector_type(4))) float f32x4;
typedef __attribute__((ext_vector_type(8))) short short8;
typedef __attribute__((ext_vector_type(8))) unsigned short ushort8;
typedef __attribute__((ext_vector_type(4))) unsigned short ushort4v;

#define M_ROWS 16384
#define KDIM 512
#define UDIM 512
#define IN_STRIDE 1024
#define NSTEP 16          // K / 32

__device__ __forceinline__ unsigned short f2bf(float f) {
    union { float f; unsigned u; } v; v.f = f;
    unsigned r = v.u + 0x7FFFu + ((v.u >> 16) & 1u);  // RTNE
    return (unsigned short)(r >> 16);
}

// global_load_lds, width 16 (literal required)
#define GLD16(g, l)                                                            \
    __builtin_amdgcn_global_load_lds(                                          \
        (const __attribute__((address_space(1))) void*)(g),                    \
        (__attribute__((address_space(3))) void*)(l), 16, 0, 0)

// ---------------------------------------------------------------------------
// pack kernel: blocks [0,256) pack weights; blocks [256,4352) convert x->bf16
//   A_bf  : (16384, 512) bf16 row-major
//   Wp    : [u_blk 8][kt 16][slot 512] x 16B; slot s -> jj=s>>2, phys p=s&3,
//           logical slot sl = p ^ ((jj>>1)&3); holds w(k0+sl*8..+8, u(jj))
// ---------------------------------------------------------------------------
__global__ __launch_bounds__(256) void pack_all(
    const float* __restrict__ inp,
    const float* __restrict__ w_z,
    const float* __restrict__ w_h,
    unsigned short* __restrict__ A_bf,
    unsigned short* __restrict__ Wp)
{
    const int bid = blockIdx.x;
    if (bid < 256) {
        // ---- pack weights ----
        int tid = bid * 256 + threadIdx.x;     // [0, 65536)
        int s   = tid & 511;
        int kt  = (tid >> 9) & 15;
        int ub  = tid >> 13;
        int jj  = s >> 2;
        int sl  = (s & 3) ^ ((jj >> 1) & 3);
        int k   = kt * 32 + sl * 8;
        const float* w = ((jj >> 5) & 1) ? w_h : w_z;
        int u = ub * 64 + ((jj >> 6) << 5) + (jj & 31);
        ushort8 v;
#pragma unroll
        for (int i = 0; i < 8; ++i)
            v[i] = f2bf(w[(size_t)(k + i) * UDIM + u]);
        *reinterpret_cast<ushort8*>(Wp + (size_t)tid * 8) = v;
    } else {
        // ---- convert x (first half of each input row) to bf16 ----
        int tid = (bid - 256) * 256 + threadIdx.x;  // [0, 16384*64)
        int row = tid >> 6;
        int c8  = (tid & 63) << 3;
        const float* p = inp + (size_t)row * IN_STRIDE + c8;
        f32x4 a = *reinterpret_cast<const f32x4*>(p);
        f32x4 b = *reinterpret_cast<const f32x4*>(p + 4);
        ushort8 v;
        v[0] = f2bf(a[0]); v[1] = f2bf(a[1]); v[2] = f2bf(a[2]); v[3] = f2bf(a[3]);
        v[4] = f2bf(b[0]); v[5] = f2bf(b[1]); v[6] = f2bf(b[2]); v[7] = f2bf(b[3]);
        *reinterpret_cast<ushort8*>(A_bf + (size_t)row * KDIM + c8) = v;
    }
}

// ---------------------------------------------------------------------------
// GEMM: 128(M) x 128(jj) tile, BK=32, 4 waves, 16x16x32 bf16 MFMA,
// global_load_lds double-buffered, 2-phase template, XOR-swizzled slots.
// ---------------------------------------------------------------------------
__global__ __launch_bounds__(256) void gru_gemm(
    const unsigned short* __restrict__ A,   // (16384, 512) bf16
    const unsigned short* __restrict__ Wp,  // packed weights
    const float* __restrict__ b_z,
    const float* __restrict__ b_h,
    float* __restrict__ out)
{
    __shared__ __align__(16) unsigned short shA[2][4096];  // [128 rows][32 k] per buf
    __shared__ __align__(16) unsigned short shB[2][4096];  // [128 jj ][32 k] per buf

    const int tid  = threadIdx.x;
    const int lane = tid & 63;
    const int wid  = tid >> 6;
    const int wm   = wid >> 1;
    const int wn   = wid & 1;

    // XCD-aware bijective swizzle: all 8 u-blocks of a row-panel on one XCD
    const int d  = blockIdx.x;           // [0,1024)
    const int bx = (d >> 3) & 7;         // u-block
    const int by = (d & 7) * 16 + (d >> 6);  // row-block
    const int u0   = bx * 64;
    const int brow = by * 128;

    // staging geometry: physical slot s = wid*128 + i*64 + lane, i in {0,1}
    const int s0 = wid * 128 + lane;
    const int s1 = s0 + 64;
    const int r0 = s0 >> 2, r1 = s1 >> 2;
    const int sl0 = (s0 & 3) ^ ((r0 >> 1) & 3);
    const int sl1 = (s1 & 3) ^ ((r1 >> 1) & 3);
    const unsigned short* a0 = A + (size_t)(brow + r0) * KDIM + sl0 * 8;
    const unsigned short* a1 = A + (size_t)(brow + r1) * KDIM + sl1 * 8;
    const unsigned short* bs = Wp + (size_t)bx * 16 * 4096 + (size_t)s0 * 8;

    unsigned short* ldA = &shA[0][0] ;  // indexed per call
    (void)ldA;

    f32x4 acc[4][4];
#pragma unroll
    for (int m = 0; m < 4; ++m)
#pragma unroll
        for (int n = 0; n < 4; ++n)
            acc[m][n] = (f32x4){0.f, 0.f, 0.f, 0.f};

    auto STAGE = [&](int b, int t) {
        GLD16(a0 + t * 32, &shA[b][wid * 1024]);
        GLD16(a1 + t * 32, &shA[b][wid * 1024 + 512]);
        GLD16(bs + (size_t)t * 4096, &shB[b][wid * 1024]);
        GLD16(bs + (size_t)t * 4096 + 512, &shB[b][wid * 1024 + 512]);
    };

    // fragment read offsets (ushort units), swizzle baked in
    const int fr = lane & 15;
    const int ks = lane >> 4;
    const int xo = (fr >> 1) & 3;           // == (row>>1)&3 for all m,n
    int aoff[4], boff[4];
#pragma unroll
    for (int m = 0; m < 4; ++m) {
        int row = wm * 64 + m * 16 + fr;
        aoff[m] = row * 32 + ((ks ^ xo) << 3);
    }
#pragma unroll
    for (int n = 0; n < 4; ++n) {
        int row = wn * 64 + n * 16 + fr;
        boff[n] = row * 32 + ((ks ^ xo) << 3);
    }

    STAGE(0, 0);
    __syncthreads();

    int buf = 0;
    for (int t = 0; t < NSTEP; ++t) {
        if (t + 1 < NSTEP) STAGE(buf ^ 1, t + 1);   // loads in flight over MFMA
        short8 af[4], bfrag[4];
#pragma unroll
        for (int m = 0; m < 4; ++m)
            af[m] = *reinterpret_cast<const short8*>(&shA[buf][aoff[m]]);
#pragma unroll
        for (int n = 0; n < 4; ++n)
            bfrag[n] = *reinterpret_cast<const short8*>(&shB[buf][boff[n]]);
#pragma unroll
        for (int m = 0; m < 4; ++m)
#pragma unroll
            for (int n = 0; n < 4; ++n)
                acc[m][n] = __builtin_amdgcn_mfma_f32_16x16x32_bf16(af[m], bfrag[n], acc[m][n], 0, 0, 0);
        __syncthreads();   // drains vmcnt (next tile ready) + LDS read/write fence
        buf ^= 1;
    }

    // ---- epilogue: seq = sigmoid(z)*tanh(h); fwd = [seq | 0]; seq dup ----
    float* fwd = out;
    float* seq = out + (size_t)M_ROWS * 1024;
    const int fq = lane >> 4;
#pragma unroll
    for (int p = 0; p < 2; ++p) {
        int u = u0 + wn * 32 + p * 16 + fr;
        float bz = b_z[u];
        float bh = b_h[u];
#pragma unroll
        for (int m = 0; m < 4; ++m) {
            int row0 = brow + wm * 64 + m * 16 + fq * 4;
            f32x4 az = acc[m][p];
            f32x4 ah = acc[m][p + 2];
#pragma unroll
            for (int j = 0; j < 4; ++j) {
                float zt = 1.f / (1.f + __expf(-(az[j] + bz)));
                float e  = __expf(2.f * (ah[j] + bh));
                float ht = 1.f - 2.f / (e + 1.f);
                float s  = zt * ht;
                size_t rr = (size_t)(row0 + j);
                fwd[rr * 1024 + u]       = s;
                fwd[rr * 1024 + 512 + u] = 0.f;
                seq[rr * 512 + u]        = s;
            }
        }
    }
}

// ---------------------------------------------------------------------------
// Legacy fallback (round-1 kernel) if ws is too small
// ---------------------------------------------------------------------------
#define LDSS 40
__global__ __launch_bounds__(256) void gru_fused_legacy(
    const float* __restrict__ inp, const float* __restrict__ w_z,
    const float* __restrict__ b_z, const float* __restrict__ w_h,
    const float* __restrict__ b_h, float* __restrict__ out)
{
    __shared__ __align__(16) unsigned short Asl[2][128][LDSS];
    __shared__ __align__(16) unsigned short Bsl[2][128][LDSS];
    const int tid = threadIdx.x, lane = tid & 63, wid = tid >> 6;
    const int wm = wid >> 1, wn = wid & 1;
    const int u0 = blockIdx.x * 64, brow = blockIdx.y * 128;
    f32x4 acc[4][4];
#pragma unroll
    for (int m = 0; m < 4; ++m)
#pragma unroll
        for (int n = 0; n < 4; ++n) acc[m][n] = (f32x4){0.f,0.f,0.f,0.f};
    f32x4 rA[4], rB[4];
#define STAGE_LOAD(kt) { const int k0_=(kt)*32; \
    _Pragma("unroll") for (int it=0; it<4; ++it){ int idx=tid+256*it; int r=idx>>3,c=(idx&7)<<2; \
        rA[it]=*reinterpret_cast<const f32x4*>(inp+(size_t)(brow+r)*IN_STRIDE+k0_+c);} \
    _Pragma("unroll") for (int it=0; it<4; ++it){ int idx=tid+256*it; int jj=idx&127; int k4=(idx>>7)<<2; \
        const float* w_=((jj>>5)&1)?w_h:w_z; int u_=u0+((jj>>6)<<5)+(jj&31); \
        const float* p_=w_+(size_t)(k0_+k4)*UDIM+u_; \
        rB[it][0]=p_[0]; rB[it][1]=p_[UDIM]; rB[it][2]=p_[2*UDIM]; rB[it][3]=p_[3*UDIM];} }
#define STAGE_WRITE(bufi) { \
    _Pragma("unroll") for (int it=0; it<4; ++it){ int idx=tid+256*it; int r=idx>>3,c=(idx&7)<<2; ushort4v v; \
        v[0]=f2bf(rA[it][0]); v[1]=f2bf(rA[it][1]); v[2]=f2bf(rA[it][2]); v[3]=f2bf(rA[it][3]); \
        *reinterpret_cast<ushort4v*>(&Asl[bufi][r][c])=v;} \
    _Pragma("unroll") for (int it=0; it<4; ++it){ int idx=tid+256*it; int jj=idx&127; int k4=(idx>>7)<<2; ushort4v v; \
        v[0]=f2bf(rB[it][0]); v[1]=f2bf(rB[it][1]); v[2]=f2bf(rB[it][2]); v[3]=f2bf(rB[it][3]); \
        *reinterpret_cast<ushort4v*>(&Bsl[bufi][jj][k4])=v;} }
    STAGE_LOAD(0); STAGE_WRITE(0);
    const int fr = lane & 15, koff = (lane >> 4) << 3;
    for (int kt = 0; kt < NSTEP; ++kt) {
        if (kt + 1 < NSTEP) STAGE_LOAD(kt + 1);
        __syncthreads();
        const int buf = kt & 1;
        short8 af[4], bfr[4];
#pragma unroll
        for (int m = 0; m < 4; ++m) af[m] = *reinterpret_cast<const short8*>(&Asl[buf][wm*64+m*16+fr][koff]);
#pragma unroll
        for (int n = 0; n < 4; ++n) bfr[n] = *reinterpret_cast<const short8*>(&Bsl[buf][wn*64+n*16+fr][koff]);
#pragma unroll
        for (int m = 0; m < 4; ++m)
#pragma unroll
            for (int n = 0; n < 4; ++n)
                acc[m][n] = __builtin_amdgcn_mfma_f32_16x16x32_bf16(af[m], bfr[n], acc[m][n], 0, 0, 0);
        if (kt + 1 < NSTEP) STAGE_WRITE((kt + 1) & 1);
    }
    float* fwd = out; float* seq = out + (size_t)M_ROWS * 1024;
    const int fq = lane >> 4;
#pragma unroll
    for (int p = 0; p < 2; ++p) {
        int u = u0 + wn * 32 + p * 16 + fr;
        float bz = b_z[u], bh = b_h[u];
#pragma unroll
        for (int m = 0; m < 4; ++m) {
            int row0 = brow + wm * 64 + m * 16 + fq * 4;
            f32x4 az = acc[m][p], ah = acc[m][p + 2];
#pragma unroll
            for (int j = 0; j < 4; ++j) {
                float zt = 1.f / (1.f + __expf(-(az[j] + bz)));
                float e  = __expf(2.f * (ah[j] + bh));
                float s  = zt * (1.f - 2.f / (e + 1.f));
                size_t rr = (size_t)(row0 + j);
                fwd[rr * 1024 + u] = s;
                fwd[rr * 1024 + 512 + u] = 0.f;
                seq[rr * 512 + u] = s;
            }
        }
    }
}

extern "C" void kernel_launch(void* const* d_in, const int* in_sizes, int n_in,
                              void* d_out, int out_size, void* d_ws, size_t ws_size,
                              hipStream_t stream) {
    const float* inp = (const float*)d_in[0];
    const float* w_z = (const float*)d_in[2];
    const float* b_z = (const float*)d_in[4];
    const float* w_h = (const float*)d_in[8];
    const float* b_h = (const float*)d_in[10];
    float* out = (float*)d_out;

    const size_t needA = (size_t)M_ROWS * KDIM * 2;        // 16,777,216 B
    const size_t needB = (size_t)8 * 16 * 512 * 16;        //  1,048,576 B
    if (ws_size >= needA + needB) {
        unsigned short* A_bf = (unsigned short*)d_ws;
        unsigned short* Wp   = (unsigned short*)((char*)d_ws + needA);
        hipLaunchKernelGGL(pack_all, dim3(256 + 4096), dim3(256), 0, stream,
                           inp, w_z, w_h, A_bf, Wp);
        hipLaunchKernelGGL(gru_gemm, dim3(1024), dim3(256), 0, stream,
                           A_bf, Wp, b_z, b_h, out);
    } else {
        hipLaunchKernelGGL(gru_fused_legacy, dim3(8, 128), dim3(256), 0, stream,
                           inp, w_z, b_z, w_h, b_h, out);
    }
}

// Round 4
// 46.537 us; speedup vs baseline: 1.4129x; 1.1612x over previous
//
#include <hip/hip_runtime.h>

typedef __attribute__((ext_vector_type(4))) float f32x4;
typedef __attribute__((ext_vector_type(8))) short short8;
typedef __attribute__((ext_vector_type(8))) unsigned short ushort8;
typedef __attribute__((ext_vector_type(4))) unsigned short ushort4v;

#define M_ROWS 16384
#define KDIM 512
#define UDIM 512
#define IN_STRIDE 1024
#define NSTEP 16          // K / 32

__device__ __forceinline__ unsigned short f2bf(float f) {
    union { float f; unsigned u; } v; v.f = f;
    unsigned r = v.u + 0x7FFFu + ((v.u >> 16) & 1u);  // RTNE
    return (unsigned short)(r >> 16);
}

// global_load_lds, width 16 (literal required)
#define GLD16(g, l)                                                            \
    __builtin_amdgcn_global_load_lds(                                          \
        (const __attribute__((address_space(1))) void*)(g),                    \
        (__attribute__((address_space(3))) void*)(l), 16, 0, 0)

// ---------------------------------------------------------------------------
// pack kernel
//  blocks [0,256):    pack weights  Wp[ub 8][kt 16][s 512] x 16B
//  blocks [256,4352): pack x -> Ap[by 128][kt 16][s 512] x 16B (bf16)
// Both packed in the EXACT linear order gru_gemm's global_load_lds consumes,
// with the LDS XOR-swizzle pre-baked into the k-slot order.
// ---------------------------------------------------------------------------
__global__ __launch_bounds__(256) void pack_all(
    const float* __restrict__ inp,
    const float* __restrict__ w_z,
    const float* __restrict__ w_h,
    unsigned short* __restrict__ Ap,
    unsigned short* __restrict__ Wp)
{
    const int bid = blockIdx.x;
    if (bid < 256) {
        int tid = bid * 256 + threadIdx.x;     // [0, 65536)
        int s   = tid & 511;
        int kt  = (tid >> 9) & 15;
        int ub  = tid >> 13;
        int jj  = s >> 2;
        int sl  = (s & 3) ^ ((jj >> 1) & 3);
        int k   = kt * 32 + sl * 8;
        const float* w = ((jj >> 5) & 1) ? w_h : w_z;
        int u = ub * 64 + ((jj >> 6) << 5) + (jj & 31);
        ushort8 v;
#pragma unroll
        for (int i = 0; i < 8; ++i)
            v[i] = f2bf(w[(size_t)(k + i) * UDIM + u]);
        *reinterpret_cast<ushort8*>(Wp + (size_t)tid * 8) = v;
    } else {
        int g   = (bid - 256) * 256 + threadIdx.x;   // [0, 1048576)
        int by  = g >> 13;
        int rem = g & 8191;
        int kt  = rem >> 9;
        int s   = rem & 511;
        int row = by * 128 + (s >> 2);
        int sl  = (s & 3) ^ ((s >> 3) & 3);
        int k   = kt * 32 + sl * 8;
        const float* p = inp + (size_t)row * IN_STRIDE + k;
        f32x4 a = *reinterpret_cast<const f32x4*>(p);
        f32x4 b = *reinterpret_cast<const f32x4*>(p + 4);
        ushort8 v;
        v[0] = f2bf(a[0]); v[1] = f2bf(a[1]); v[2] = f2bf(a[2]); v[3] = f2bf(a[3]);
        v[4] = f2bf(b[0]); v[5] = f2bf(b[1]); v[6] = f2bf(b[2]); v[7] = f2bf(b[3]);
        *reinterpret_cast<ushort8*>(Ap + (size_t)g * 8) = v;
    }
}

// ---------------------------------------------------------------------------
// GEMM: 128(M) x 128(jj) tile, BK=32, 4 waves, 3-buffer ring, depth-2
// prefetch with counted vmcnt(4). ALL barriers are asm-fenced (compiler
// memory fence) and each wave drains its own lgkmcnt before the barrier —
// closes the cross-wave LDS overwrite race from round 3.
// ---------------------------------------------------------------------------
__global__ __launch_bounds__(256, 3) void gru_gemm(
    const unsigned short* __restrict__ Ap,  // packed x (bf16, k-tiled)
    const unsigned short* __restrict__ Wp,  // packed weights
    const float* __restrict__ b_z,
    const float* __restrict__ b_h,
    float* __restrict__ out)
{
    __shared__ __align__(16) unsigned char smem[49152];
    unsigned short* shA = (unsigned short*)smem;            // 3 bufs x 4096 ushorts
    unsigned short* shB = (unsigned short*)(smem + 24576);  // 3 bufs x 4096 ushorts

    const int tid  = threadIdx.x;
    const int lane = tid & 63;
    const int wid  = tid >> 6;
    const int wm   = wid >> 1;
    const int wn   = wid & 1;

    // XCD-aware swizzle: the 8 u-blocks of a row-panel land on one XCD
    const int d  = blockIdx.x;               // [0,1024)
    const int bx = (d >> 3) & 7;             // u-block
    const int by = (d & 7) * 16 + (d >> 6);  // row-panel
    const int u0   = bx * 64;
    const int brow = by * 128;

    const int s0 = wid * 128 + lane;
    const unsigned short* ap = Ap + (size_t)by * 65536 + (size_t)s0 * 8;
    const unsigned short* bp = Wp + (size_t)bx * 65536 + (size_t)s0 * 8;

    f32x4 acc[4][4];
#pragma unroll
    for (int m = 0; m < 4; ++m)
#pragma unroll
        for (int n = 0; n < 4; ++n)
            acc[m][n] = (f32x4){0.f, 0.f, 0.f, 0.f};

    auto STAGE = [&](int b, int t) {
        GLD16(ap + t * 4096,       shA + b * 4096 + wid * 1024);
        GLD16(ap + t * 4096 + 512, shA + b * 4096 + wid * 1024 + 512);
        GLD16(bp + t * 4096,       shB + b * 4096 + wid * 1024);
        GLD16(bp + t * 4096 + 512, shB + b * 4096 + wid * 1024 + 512);
    };

    // fragment read offsets (ushort units), XOR-swizzle baked in
    const int fr = lane & 15;
    const int ks = lane >> 4;
    const int xo = (fr >> 1) & 3;
    int aoff[4], boff[4];
#pragma unroll
    for (int m = 0; m < 4; ++m)
        aoff[m] = (wm * 64 + m * 16 + fr) * 32 + ((ks ^ xo) << 3);
#pragma unroll
    for (int n = 0; n < 4; ++n)
        boff[n] = (wn * 64 + n * 16 + fr) * 32 + ((ks ^ xo) << 3);

    // prologue: two stages in flight, wait only for the first, fenced barrier
    STAGE(0, 0);
    STAGE(1, 1);
    asm volatile("s_waitcnt vmcnt(4)" ::: "memory");
    asm volatile("s_barrier" ::: "memory");

#pragma unroll
    for (int t = 0; t < NSTEP; ++t) {
        if (t + 2 < NSTEP) STAGE((t + 2) % 3, t + 2);  // depth-2 prefetch
        const int buf = t % 3;
        short8 af[4], bfrag[4];
#pragma unroll
        for (int m = 0; m < 4; ++m)
            af[m] = *reinterpret_cast<const short8*>(&shA[buf * 4096 + aoff[m]]);
#pragma unroll
        for (int n = 0; n < 4; ++n)
            bfrag[n] = *reinterpret_cast<const short8*>(&shB[buf * 4096 + boff[n]]);
#pragma unroll
        for (int m = 0; m < 4; ++m)
#pragma unroll
            for (int n = 0; n < 4; ++n)
                acc[m][n] = __builtin_amdgcn_mfma_f32_16x16x32_bf16(af[m], bfrag[n], acc[m][n], 0, 0, 0);
        if (t + 1 < NSTEP) {
            // my ds_reads of buf t are complete before I cross the barrier
            asm volatile("s_waitcnt lgkmcnt(0)" ::: "memory");
            if (t + 2 < NSTEP) {
                // stage t+1 landed; stage t+2 (4 loads) stays in flight
                asm volatile("s_waitcnt vmcnt(4)" ::: "memory");
            } else {
                asm volatile("s_waitcnt vmcnt(0)" ::: "memory");
            }
            asm volatile("s_barrier" ::: "memory");
        }
    }

    __syncthreads();   // full fence before LDS reuse (drains lgkm+vm per wave)

    // ---- epilogue: s = sigmoid(z+bz)*tanh(h+bh) in regs -> LDS plane ----
    float* plane = (float*)smem;   // [128][68] f32, stride 68 breaks conflicts
    const int fq = lane >> 4;
#pragma unroll
    for (int p = 0; p < 2; ++p) {
        int ucol = wn * 32 + p * 16 + fr;
        float bz = b_z[u0 + ucol];
        float bh = b_h[u0 + ucol];
#pragma unroll
        for (int m = 0; m < 4; ++m) {
            int row0 = wm * 64 + m * 16 + fq * 4;
            f32x4 az = acc[m][p];
            f32x4 ah = acc[m][p + 2];
#pragma unroll
            for (int j = 0; j < 4; ++j) {
                float zt = 1.f / (1.f + __expf(-(az[j] + bz)));
                float e  = __expf(2.f * (ah[j] + bh));
                float s  = zt * (1.f - 2.f / (e + 1.f));
                plane[(row0 + j) * 68 + ucol] = s;
            }
        }
    }
    __syncthreads();

    // ---- transposed float4 stores: 256B contiguous per quarter-wave ----
    float* fwd = out;
    float* seq = out + (size_t)M_ROWS * 1024;
    const f32x4 z4 = (f32x4){0.f, 0.f, 0.f, 0.f};
    const int c4 = (tid & 15) * 4;
#pragma unroll
    for (int it = 0; it < 8; ++it) {
        int row = it * 16 + (tid >> 4);
        f32x4 v = *reinterpret_cast<const f32x4*>(&plane[row * 68 + c4]);
        size_t grow = (size_t)(brow + row);
        *reinterpret_cast<f32x4*>(&fwd[grow * 1024 + u0 + c4])       = v;
        *reinterpret_cast<f32x4*>(&fwd[grow * 1024 + 512 + u0 + c4]) = z4;
        *reinterpret_cast<f32x4*>(&seq[grow * 512 + u0 + c4])        = v;
    }
}

// ---------------------------------------------------------------------------
// Legacy fallback (round-1 kernel) if ws is too small
// ---------------------------------------------------------------------------
#define LDSS 40
__global__ __launch_bounds__(256) void gru_fused_legacy(
    const float* __restrict__ inp, const float* __restrict__ w_z,
    const float* __restrict__ b_z, const float* __restrict__ w_h,
    const float* __restrict__ b_h, float* __restrict__ out)
{
    __shared__ __align__(16) unsigned short Asl[2][128][LDSS];
    __shared__ __align__(16) unsigned short Bsl[2][128][LDSS];
    const int tid = threadIdx.x, lane = tid & 63, wid = tid >> 6;
    const int wm = wid >> 1, wn = wid & 1;
    const int u0 = blockIdx.x * 64, brow = blockIdx.y * 128;
    f32x4 acc[4][4];
#pragma unroll
    for (int m = 0; m < 4; ++m)
#pragma unroll
        for (int n = 0; n < 4; ++n) acc[m][n] = (f32x4){0.f,0.f,0.f,0.f};
    f32x4 rA[4], rB[4];
#define STAGE_LOAD(kt) { const int k0_=(kt)*32; \
    _Pragma("unroll") for (int it=0; it<4; ++it){ int idx=tid+256*it; int r=idx>>3,c=(idx&7)<<2; \
        rA[it]=*reinterpret_cast<const f32x4*>(inp+(size_t)(brow+r)*IN_STRIDE+k0_+c);} \
    _Pragma("unroll") for (int it=0; it<4; ++it){ int idx=tid+256*it; int jj=idx&127; int k4=(idx>>7)<<2; \
        const float* w_=((jj>>5)&1)?w_h:w_z; int u_=u0+((jj>>6)<<5)+(jj&31); \
        const float* p_=w_+(size_t)(k0_+k4)*UDIM+u_; \
        rB[it][0]=p_[0]; rB[it][1]=p_[UDIM]; rB[it][2]=p_[2*UDIM]; rB[it][3]=p_[3*UDIM];} }
#define STAGE_WRITE(bufi) { \
    _Pragma("unroll") for (int it=0; it<4; ++it){ int idx=tid+256*it; int r=idx>>3,c=(idx&7)<<2; ushort4v v; \
        v[0]=f2bf(rA[it][0]); v[1]=f2bf(rA[it][1]); v[2]=f2bf(rA[it][2]); v[3]=f2bf(rA[it][3]); \
        *reinterpret_cast<ushort4v*>(&Asl[bufi][r][c])=v;} \
    _Pragma("unroll") for (int it=0; it<4; ++it){ int idx=tid+256*it; int jj=idx&127; int k4=(idx>>7)<<2; ushort4v v; \
        v[0]=f2bf(rB[it][0]); v[1]=f2bf(rB[it][1]); v[2]=f2bf(rB[it][2]); v[3]=f2bf(rB[it][3]); \
        *reinterpret_cast<ushort4v*>(&Bsl[bufi][jj][k4])=v;} }
    STAGE_LOAD(0); STAGE_WRITE(0);
    const int fr = lane & 15, koff = (lane >> 4) << 3;
    for (int kt = 0; kt < NSTEP; ++kt) {
        if (kt + 1 < NSTEP) STAGE_LOAD(kt + 1);
        __syncthreads();
        const int buf = kt & 1;
        short8 af[4], bfr[4];
#pragma unroll
        for (int m = 0; m < 4; ++m) af[m] = *reinterpret_cast<const short8*>(&Asl[buf][wm*64+m*16+fr][koff]);
#pragma unroll
        for (int n = 0; n < 4; ++n) bfr[n] = *reinterpret_cast<const short8*>(&Bsl[buf][wn*64+n*16+fr][koff]);
#pragma unroll
        for (int m = 0; m < 4; ++m)
#pragma unroll
            for (int n = 0; n < 4; ++n)
                acc[m][n] = __builtin_amdgcn_mfma_f32_16x16x32_bf16(af[m], bfr[n], acc[m][n], 0, 0, 0);
        if (kt + 1 < NSTEP) STAGE_WRITE((kt + 1) & 1);
    }
    float* fwd = out; float* seq = out + (size_t)M_ROWS * 1024;
    const int fq = lane >> 4;
#pragma unroll
    for (int p = 0; p < 2; ++p) {
        int u = u0 + wn * 32 + p * 16 + fr;
        float bz = b_z[u], bh = b_h[u];
#pragma unroll
        for (int m = 0; m < 4; ++m) {
            int row0 = brow + wm * 64 + m * 16 + fq * 4;
            f32x4 az = acc[m][p], ah = acc[m][p + 2];
#pragma unroll
            for (int j = 0; j < 4; ++j) {
                float zt = 1.f / (1.f + __expf(-(az[j] + bz)));
                float e  = __expf(2.f * (ah[j] + bh));
                float s  = zt * (1.f - 2.f / (e + 1.f));
                size_t rr = (size_t)(row0 + j);
                fwd[rr * 1024 + u] = s;
                fwd[rr * 1024 + 512 + u] = 0.f;
                seq[rr * 512 + u] = s;
            }
        }
    }
}

extern "C" void kernel_launch(void* const* d_in, const int* in_sizes, int n_in,
                              void* d_out, int out_size, void* d_ws, size_t ws_size,
                              hipStream_t stream) {
    const float* inp = (const float*)d_in[0];
    const float* w_z = (const float*)d_in[2];
    const float* b_z = (const float*)d_in[4];
    const float* w_h = (const float*)d_in[8];
    const float* b_h = (const float*)d_in[10];
    float* out = (float*)d_out;

    const size_t needA = (size_t)M_ROWS * KDIM * 2;        // 16 MiB
    const size_t needB = (size_t)8 * 16 * 512 * 16;        //  1 MiB
    if (ws_size >= needA + needB) {
        unsigned short* Ap = (unsigned short*)d_ws;
        unsigned short* Wp = (unsigned short*)((char*)d_ws + needA);
        hipLaunchKernelGGL(pack_all, dim3(256 + 4096), dim3(256), 0, stream,
                           inp, w_z, w_h, Ap, Wp);
        hipLaunchKernelGGL(gru_gemm, dim3(1024), dim3(256), 0, stream,
                           Ap, Wp, b_z, b_h, out);
    } else {
        hipLaunchKernelGGL(gru_fused_legacy, dim3(8, 128), dim3(256), 0, stream,
                           inp, w_z, b_z, w_h, b_h, out);
    }
}